// Round 1
// baseline (549.023 us; speedup 1.0000x reference)
//
#include <hip/hip_runtime.h>
#include <hip/hip_bf16.h>

// PointTransformerBlock: B=2, N=8192, K=16, C_IN=64, C_OUT=256, HID=256,
// L=2, HEADS=8, DKQV=32, D=256.  All activations fp32.

constexpr int NPTS   = 8192;
constexpr int BPTS   = 2 * NPTS;   // 16384 total points (B*N)
constexpr int HIDD   = 256;        // HID == D == C_OUT == 256
constexpr int KNN    = 16;

// ---------------------------------------------------------------------------
// Tiled fp32 GEMM: C[M,N] = A[M,Kd] @ W[Kd,N] + bias (+res) (+leakyrelu)
// BM=BN=64, BK=16, 256 threads, 4x4 micro-tile per thread.
// M % 64 == 0, N % 64 == 0, Kd % 16 == 0 (true for all our shapes).
// ---------------------------------------------------------------------------
template<bool RES, bool LRELU>
__global__ __launch_bounds__(256) void gemm_bias_kernel(
    const float* __restrict__ A, const float* __restrict__ W,
    const float* __restrict__ bias, const float* __restrict__ resp,
    float* __restrict__ C, int M, int N, int Kd)
{
    __shared__ float As[64][17];   // +1 pad
    __shared__ float Ws[16][64];

    const int tid = threadIdx.x;
    const int tx  = tid & 15;      // 0..15 (col group)
    const int ty  = tid >> 4;      // 0..15 (row group)
    const int bm  = blockIdx.y * 64;
    const int bn  = blockIdx.x * 64;

    // staging indices
    const int ar = tid >> 2;         // 0..63
    const int ak = (tid & 3) * 4;    // 0,4,8,12
    const int wk = tid >> 4;         // 0..15
    const int wc = (tid & 15) * 4;   // 0..60

    float acc[4][4] = {};

    for (int k0 = 0; k0 < Kd; k0 += 16) {
        const float4 a4 = *(const float4*)&A[(size_t)(bm + ar) * Kd + k0 + ak];
        const float4 w4 = *(const float4*)&W[(size_t)(k0 + wk) * N + bn + wc];
        As[ar][ak + 0] = a4.x; As[ar][ak + 1] = a4.y;
        As[ar][ak + 2] = a4.z; As[ar][ak + 3] = a4.w;
        *(float4*)&Ws[wk][wc] = w4;
        __syncthreads();

        #pragma unroll
        for (int kk = 0; kk < 16; ++kk) {
            const float4 w = *(const float4*)&Ws[kk][tx * 4];
            const float a0 = As[ty * 4 + 0][kk];
            const float a1 = As[ty * 4 + 1][kk];
            const float a2 = As[ty * 4 + 2][kk];
            const float a3 = As[ty * 4 + 3][kk];
            acc[0][0] += a0 * w.x; acc[0][1] += a0 * w.y; acc[0][2] += a0 * w.z; acc[0][3] += a0 * w.w;
            acc[1][0] += a1 * w.x; acc[1][1] += a1 * w.y; acc[1][2] += a1 * w.z; acc[1][3] += a1 * w.w;
            acc[2][0] += a2 * w.x; acc[2][1] += a2 * w.y; acc[2][2] += a2 * w.z; acc[2][3] += a2 * w.w;
            acc[3][0] += a3 * w.x; acc[3][1] += a3 * w.y; acc[3][2] += a3 * w.z; acc[3][3] += a3 * w.w;
        }
        __syncthreads();
    }

    const int col = bn + tx * 4;
    const float b0 = bias[col + 0], b1 = bias[col + 1], b2 = bias[col + 2], b3 = bias[col + 3];
    #pragma unroll
    for (int i = 0; i < 4; ++i) {
        const int row = bm + ty * 4 + i;
        float4 c;
        c.x = acc[i][0] + b0; c.y = acc[i][1] + b1;
        c.z = acc[i][2] + b2; c.w = acc[i][3] + b3;
        if (RES) {
            const float4 r = *(const float4*)&resp[(size_t)row * N + col];
            c.x += r.x; c.y += r.y; c.z += r.z; c.w += r.w;
        }
        if (LRELU) {
            c.x = c.x > 0.f ? c.x : 0.01f * c.x;
            c.y = c.y > 0.f ? c.y : 0.01f * c.y;
            c.z = c.z > 0.f ? c.z : 0.01f * c.z;
            c.w = c.w > 0.f ? c.w : 0.01f * c.w;
        }
        *(float4*)&C[(size_t)row * N + col] = c;
    }
}

// ---------------------------------------------------------------------------
// KNN attention: one block (256 threads) per point; thread d = channel.
// logits[h][k] = (q[d]/sqrt(32)) . (k_nb[d]+pos[d]) reduced over the 32 lanes
// of head h; softmax over K=16; o[d] = sum_k attn * (v_nb[d]+pos[d]).
// ---------------------------------------------------------------------------
__global__ __launch_bounds__(256) void knn_attn_kernel(
    const float* __restrict__ xyz,   // [BPTS,3]
    const int*   __restrict__ idx,   // [BPTS,KNN]
    const float* __restrict__ q,     // [BPTS,256]
    const float* __restrict__ kbuf,  // [BPTS,256]
    const float* __restrict__ vbuf,  // [BPTS,256]
    const float* __restrict__ Wp,    // [3,256]
    const float* __restrict__ bp,    // [256]
    float* __restrict__ o)           // [BPTS,256]
{
    const int p = blockIdx.x;          // point index in [0, BPTS)
    const int b = p >> 13;             // batch (N=8192)
    const int d = threadIdx.x;         // channel 0..255
    const int h = d >> 5;              // head 0..7

    __shared__ int   s_row[KNN];
    __shared__ float s_rel[KNN][3];
    __shared__ float s_logit[8][KNN];

    if (d < KNN) {
        const int j = idx[p * KNN + d];
        const int jrow = b * NPTS + j;
        s_row[d] = jrow;
        s_rel[d][0] = xyz[p * 3 + 0] - xyz[jrow * 3 + 0];
        s_rel[d][1] = xyz[p * 3 + 1] - xyz[jrow * 3 + 1];
        s_rel[d][2] = xyz[p * 3 + 2] - xyz[jrow * 3 + 2];
    }
    __syncthreads();

    const float wp0 = Wp[d], wp1 = Wp[256 + d], wp2 = Wp[512 + d];
    const float bpd = bp[d];
    const float qd  = q[(size_t)p * 256 + d] * 0.1767766952966369f; // 1/sqrt(32)

    float kh[KNN], vh[KNN];
    #pragma unroll
    for (int kk = 0; kk < KNN; ++kk) {
        const int jrow = s_row[kk];
        const float pos = s_rel[kk][0] * wp0 + s_rel[kk][1] * wp1
                        + s_rel[kk][2] * wp2 + bpd;
        kh[kk] = kbuf[(size_t)jrow * 256 + d] + pos;
        vh[kk] = vbuf[(size_t)jrow * 256 + d] + pos;
        float prod = qd * kh[kk];
        // reduce over the 32 lanes of this head
        #pragma unroll
        for (int off = 16; off >= 1; off >>= 1)
            prod += __shfl_xor(prod, off, 32);
        if ((d & 31) == 0) s_logit[h][kk] = prod;
    }
    __syncthreads();

    float mx = -1e30f;
    #pragma unroll
    for (int kk = 0; kk < KNN; ++kk) mx = fmaxf(mx, s_logit[h][kk]);

    float accv = 0.f, denom = 0.f;
    #pragma unroll
    for (int kk = 0; kk < KNN; ++kk) {
        const float e = __expf(s_logit[h][kk] - mx);
        denom += e;
        accv  += e * vh[kk];
    }
    o[(size_t)p * 256 + d] = accv / denom;
}

// ---------------------------------------------------------------------------
extern "C" void kernel_launch(void* const* d_in, const int* in_sizes, int n_in,
                              void* d_out, int out_size, void* d_ws, size_t ws_size,
                              hipStream_t stream)
{
    const float* xyzs     = (const float*)d_in[0];
    const float* features = (const float*)d_in[1];
    const int*   k_graph  = (const int*)  d_in[2];
    const float* W_in     = (const float*)d_in[3];
    const float* b_in     = (const float*)d_in[4];
    const float* Wq       = (const float*)d_in[5];
    const float* bq       = (const float*)d_in[6];
    const float* Wk       = (const float*)d_in[7];
    const float* bk       = (const float*)d_in[8];
    const float* Wv       = (const float*)d_in[9];
    const float* bv       = (const float*)d_in[10];
    const float* Wp       = (const float*)d_in[11];
    const float* bp       = (const float*)d_in[12];
    const float* Wo       = (const float*)d_in[13];
    const float* bo       = (const float*)d_in[14];
    const float* W_out    = (const float*)d_in[15];
    const float* b_out    = (const float*)d_in[16];

    float* out = (float*)d_out;

    const size_t FSZ = (size_t)BPTS * HIDD;   // 16384*256
    float* f  = (float*)d_ws;
    float* qb = f  + FSZ;
    float* kb = qb + FSZ;
    float* vb = kb + FSZ;
    float* ob = out;                           // reuse d_out as attention scratch

    const dim3 gblk(256);
    const dim3 ggrid(HIDD / 64, BPTS / 64);    // (4, 256)

    // f = features @ W_in + b_in     [16384,64] @ [64,256]
    gemm_bias_kernel<false, false><<<ggrid, gblk, 0, stream>>>(
        features, W_in, b_in, nullptr, f, BPTS, HIDD, 64);

    for (int l = 0; l < 2; ++l) {
        const size_t wOff = (size_t)l * HIDD * HIDD;   // 65536
        const size_t bOff = (size_t)l * HIDD;          // 256
        gemm_bias_kernel<false, false><<<ggrid, gblk, 0, stream>>>(
            f, Wq + wOff, bq + bOff, nullptr, qb, BPTS, HIDD, HIDD);
        gemm_bias_kernel<false, false><<<ggrid, gblk, 0, stream>>>(
            f, Wk + wOff, bk + bOff, nullptr, kb, BPTS, HIDD, HIDD);
        gemm_bias_kernel<false, false><<<ggrid, gblk, 0, stream>>>(
            f, Wv + wOff, bv + bOff, nullptr, vb, BPTS, HIDD, HIDD);

        knn_attn_kernel<<<dim3(BPTS), gblk, 0, stream>>>(
            xyzs, k_graph, qb, kb, vb, Wp + (size_t)l * 3 * HIDD, bp + bOff, ob);

        // f = ob @ Wo + bo + f   (residual, in-place on f)
        gemm_bias_kernel<true, false><<<ggrid, gblk, 0, stream>>>(
            ob, Wo + wOff, bo + bOff, f, f, BPTS, HIDD, HIDD);
    }

    // out = leaky_relu(f @ W_out + b_out)
    gemm_bias_kernel<false, true><<<ggrid, gblk, 0, stream>>>(
        f, W_out, b_out, nullptr, out, BPTS, HIDD, HIDD);
}

// Round 2
// 192.748 us; speedup vs baseline: 2.8484x; 2.8484x over previous
//
#include <hip/hip_runtime.h>
#include <hip/hip_bf16.h>

typedef __attribute__((ext_vector_type(8))) short bf16x8;
typedef __attribute__((ext_vector_type(4))) float f32x4;
typedef unsigned int uint;

constexpr int NPTS = 8192;
constexpr int BPTS = 16384;     // B*N
constexpr int KNN  = 16;

// async global->LDS, 16B per lane; LDS dest is wave-uniform base + lane*16,
// global source is per-lane (pre-swizzled for the XOR LDS layout).
__device__ __forceinline__ void gload16(const void* g, void* l) {
    __builtin_amdgcn_global_load_lds(
        (const __attribute__((address_space(1))) unsigned int*)g,
        (__attribute__((address_space(3))) unsigned int*)l, 16, 0, 0);
}

__device__ __forceinline__ float2 bf2f2(uint u) {
    float2 r;
    r.x = __uint_as_float(u << 16);
    r.y = __uint_as_float(u & 0xffff0000u);
    return r;
}

__device__ __forceinline__ uint packbf2(float a, float b) {
    union { __hip_bfloat16 h; unsigned short u; } ua, ub;
    ua.h = __float2bfloat16(a); ub.h = __float2bfloat16(b);
    return (uint)ua.u | ((uint)ub.u << 16);
}

// ---------------------------------------------------------------------------
// bf16 MFMA GEMM: C[M,N] = A[M,KD] @ Bt[N,KD]^T + bias (+res)(+lrelu)
// 128x128 tile, BK=32, 4 waves (2x2 of 64x64), 16x16x32 MFMA, fp32 acc.
// LDS tiles XOR-swizzled: phys_slot = slot ^ ((row>>2)&3)  (4 x 16B slots/row)
// staged via global_load_lds with pre-swizzled per-lane global addresses.
// ---------------------------------------------------------------------------
template<int KD, bool RES, bool OUTF32, bool LRELU>
__global__ __launch_bounds__(256) void gemm_mfma(
    const __hip_bfloat16* __restrict__ A,   // [M, KD]
    const __hip_bfloat16* __restrict__ Bt,  // [N, KD]  (W transposed)
    const float* __restrict__ b0, const float* __restrict__ b1,
    const float* __restrict__ b2,
    const __hip_bfloat16* __restrict__ res, // [M, N] or null
    void* __restrict__ Cout, int M, int N)
{
    __shared__ __align__(16) __hip_bfloat16 As[128 * 32];
    __shared__ __align__(16) __hip_bfloat16 Bs[128 * 32];

    const int tid  = threadIdx.x;
    const int lane = tid & 63;
    const int wid  = tid >> 6;
    const int wm   = (wid >> 1) * 64;
    const int wn   = (wid & 1) * 64;
    const int bm   = blockIdx.y * 128;
    const int bn   = blockIdx.x * 128;

    // staging: load L covers LDS rows 16L..16L+15; lane l -> row 16L+(l>>2),
    // phys slot l&3 holds logical slot (l&3)^((l>>4)&3)
    const int srow  = lane >> 2;
    const int sslot = (lane & 3) ^ ((lane >> 4) & 3);

    // fragment read: row = *+ (lane&15), logical slot g=lane>>4,
    // phys slot = g ^ (((lane&15)>>2)&3)
    const int r = lane & 15;
    const int g = lane >> 4;
    const int fslot = g ^ ((r >> 2) & 3);

    f32x4 acc[4][4] = {};

    for (int k0 = 0; k0 < KD; k0 += 32) {
        #pragma unroll
        for (int t = 0; t < 2; ++t) {
            const int L   = wid * 2 + t;
            const int row = L * 16 + srow;
            gload16(&A[(size_t)(bm + row) * KD + k0 + sslot * 8],
                    (char*)As + L * 1024);
            gload16(&Bt[(size_t)(bn + row) * KD + k0 + sslot * 8],
                    (char*)Bs + L * 1024);
        }
        __syncthreads();

        bf16x8 af[4], bfr[4];
        #pragma unroll
        for (int mi = 0; mi < 4; ++mi)
            af[mi] = *(const bf16x8*)((const char*)As + (wm + mi * 16 + r) * 64 + fslot * 16);
        #pragma unroll
        for (int ni = 0; ni < 4; ++ni)
            bfr[ni] = *(const bf16x8*)((const char*)Bs + (wn + ni * 16 + r) * 64 + fslot * 16);
        #pragma unroll
        for (int mi = 0; mi < 4; ++mi)
            #pragma unroll
            for (int ni = 0; ni < 4; ++ni)
                acc[mi][ni] = __builtin_amdgcn_mfma_f32_16x16x32_bf16(
                    af[mi], bfr[ni], acc[mi][ni], 0, 0, 0);
        __syncthreads();
    }

    // epilogue: C row = (lane>>4)*4 + reg, col = lane&15 (m89-verified layout)
    #pragma unroll
    for (int ni = 0; ni < 4; ++ni) {
        const int col = bn + wn + ni * 16 + r;
        const float* bsel = (col < 256) ? b0 : (col < 512 ? b1 : b2);
        const float bias = bsel[col & 255];
        #pragma unroll
        for (int mi = 0; mi < 4; ++mi) {
            #pragma unroll
            for (int q = 0; q < 4; ++q) {
                const int row = bm + wm + mi * 16 + g * 4 + q;
                float v = acc[mi][ni][q] + bias;
                if (RES)  v += __bfloat162float(res[(size_t)row * N + col]);
                if (LRELU) v = v > 0.f ? v : 0.01f * v;
                if (OUTF32) ((float*)Cout)[(size_t)row * N + col] = v;
                else ((__hip_bfloat16*)Cout)[(size_t)row * N + col] = __float2bfloat16(v);
            }
        }
    }
}

// ---------------------------------------------------------------------------
// prep: transpose-convert all weights fp32[K][N] -> bf16[N][K], and convert
// features fp32 -> bf16.  One kernel, block = one 32x32 tile (or 1024 feats).
// ---------------------------------------------------------------------------
__global__ __launch_bounds__(256) void prep_kernel(
    const float* __restrict__ W_in, const float* __restrict__ Wq,
    const float* __restrict__ Wk,  const float* __restrict__ Wv,
    const float* __restrict__ Wo,  const float* __restrict__ W_out,
    const float* __restrict__ features,
    __hip_bfloat16* __restrict__ WtIn,  __hip_bfloat16* __restrict__ WtQKV,
    __hip_bfloat16* __restrict__ WtO,   __hip_bfloat16* __restrict__ WtOut,
    __hip_bfloat16* __restrict__ featb)
{
    const int b = blockIdx.x;
    if (b < 592) {
        const float* srcs[10] = {W_in, Wq, Wk, Wv, Wq + 65536, Wk + 65536,
                                 Wv + 65536, Wo, Wo + 65536, W_out};
        __hip_bfloat16* dsts[10] = {
            WtIn, WtQKV, WtQKV + 65536, WtQKV + 131072,
            WtQKV + 196608, WtQKV + 262144, WtQKV + 327680,
            WtO, WtO + 65536, WtOut};
        const int Ks[10]    = {64,256,256,256,256,256,256,256,256,256};
        const int start[10] = {0,16,80,144,208,272,336,400,464,528};
        int j = 0;
        #pragma unroll
        for (int i = 1; i < 10; ++i) if (b >= start[i]) j = i;
        const int t  = b - start[j];
        const int Kd = Ks[j];
        const int ntk = Kd >> 5;        // tiles along K
        const int tn = t / ntk;         // tile along N (N always 256)
        const int tk = t - tn * ntk;

        __shared__ float s[32][33];
        const int tx = threadIdx.x & 31, ty = threadIdx.x >> 5; // ty 0..7
        const float* src = srcs[j];
        #pragma unroll
        for (int i = 0; i < 4; ++i)
            s[ty + i * 8][tx] = src[(size_t)(tk * 32 + ty + i * 8) * 256 + tn * 32 + tx];
        __syncthreads();
        __hip_bfloat16* dst = dsts[j];
        #pragma unroll
        for (int i = 0; i < 4; ++i)
            dst[(size_t)(tn * 32 + ty + i * 8) * Kd + tk * 32 + tx] =
                __float2bfloat16(s[tx][ty + i * 8]);
    } else {
        const int i = (b - 592) * 1024 + threadIdx.x * 4;
        const float4 v = *(const float4*)&features[i];
        __hip_bfloat16 tmp[4] = {__float2bfloat16(v.x), __float2bfloat16(v.y),
                                 __float2bfloat16(v.z), __float2bfloat16(v.w)};
        *(uint2*)&featb[i] = *(const uint2*)tmp;
    }
}

// ---------------------------------------------------------------------------
// KNN attention, bf16 in/out. 2 points per 256-thread block; thread owns 2
// consecutive channels (bf16x2 loads). Head = 16 lanes; shfl_xor reduce.
// qkv packed per row: [q(256) | k(256) | v(256)] stride 768.
// ---------------------------------------------------------------------------
__global__ __launch_bounds__(256) void knn_attn_kernel(
    const float* __restrict__ xyz,          // [BPTS,3]
    const int*   __restrict__ idx,          // [BPTS,KNN]
    const __hip_bfloat16* __restrict__ qkv, // [BPTS,768]
    const float* __restrict__ Wp,           // [3,256]
    const float* __restrict__ bp,           // [256]
    __hip_bfloat16* __restrict__ o)         // [BPTS,256]
{
    const int pt = threadIdx.x >> 7;        // 0..1 point within block
    const int lt = threadIdx.x & 127;
    const int p  = blockIdx.x * 2 + pt;
    const int h  = lt >> 4;                 // head 0..7
    const int ch = lt * 2;                  // channel pair base

    __shared__ int   s_row[2][KNN];
    __shared__ float s_rel[2][KNN][3];
    __shared__ float s_logit[2][8][KNN];

    if (threadIdx.x < 32) {
        const int pp = threadIdx.x >> 4;
        const int kk = threadIdx.x & 15;
        const int pg = blockIdx.x * 2 + pp;
        const int bidx = pg >> 13;
        const int j = idx[pg * KNN + kk];
        const int jrow = (bidx << 13) + j;
        s_row[pp][kk] = jrow;
        s_rel[pp][kk][0] = xyz[pg * 3 + 0] - xyz[jrow * 3 + 0];
        s_rel[pp][kk][1] = xyz[pg * 3 + 1] - xyz[jrow * 3 + 1];
        s_rel[pp][kk][2] = xyz[pg * 3 + 2] - xyz[jrow * 3 + 2];
    }
    __syncthreads();

    const float wp0a = Wp[ch],     wp0b = Wp[ch + 1];
    const float wp1a = Wp[256+ch], wp1b = Wp[256+ch+1];
    const float wp2a = Wp[512+ch], wp2b = Wp[512+ch+1];
    const float bpa  = bp[ch],     bpb  = bp[ch + 1];

    const float2 qv = bf2f2(*(const uint*)&qkv[(size_t)p * 768 + ch]);
    const float qa  = qv.x * 0.1767766952966369f;   // 1/sqrt(32)
    const float qb_ = qv.y * 0.1767766952966369f;

    float2 vh[KNN];
    #pragma unroll
    for (int kk = 0; kk < KNN; ++kk) {
        const int jrow = s_row[pt][kk];
        const float rx = s_rel[pt][kk][0], ry = s_rel[pt][kk][1], rz = s_rel[pt][kk][2];
        const float posA = rx * wp0a + ry * wp1a + rz * wp2a + bpa;
        const float posB = rx * wp0b + ry * wp1b + rz * wp2b + bpb;
        const float2 kv = bf2f2(*(const uint*)&qkv[(size_t)jrow * 768 + 256 + ch]);
        const float2 vv = bf2f2(*(const uint*)&qkv[(size_t)jrow * 768 + 512 + ch]);
        vh[kk].x = vv.x + posA;
        vh[kk].y = vv.y + posB;
        float prod = qa * (kv.x + posA) + qb_ * (kv.y + posB);
        #pragma unroll
        for (int off = 8; off >= 1; off >>= 1)
            prod += __shfl_xor(prod, off, 16);
        if ((lt & 15) == 0) s_logit[pt][h][kk] = prod;
    }
    __syncthreads();

    float mx = -1e30f;
    #pragma unroll
    for (int kk = 0; kk < KNN; ++kk) mx = fmaxf(mx, s_logit[pt][h][kk]);

    float ax = 0.f, ay = 0.f, denom = 0.f;
    #pragma unroll
    for (int kk = 0; kk < KNN; ++kk) {
        const float e = __expf(s_logit[pt][h][kk] - mx);
        denom += e;
        ax += e * vh[kk].x;
        ay += e * vh[kk].y;
    }
    const float inv = 1.f / denom;
    *(uint*)&o[(size_t)p * 256 + ch] = packbf2(ax * inv, ay * inv);
}

// ---------------------------------------------------------------------------
extern "C" void kernel_launch(void* const* d_in, const int* in_sizes, int n_in,
                              void* d_out, int out_size, void* d_ws, size_t ws_size,
                              hipStream_t stream)
{
    const float* xyzs     = (const float*)d_in[0];
    const float* features = (const float*)d_in[1];
    const int*   k_graph  = (const int*)  d_in[2];
    const float* W_in     = (const float*)d_in[3];
    const float* b_in     = (const float*)d_in[4];
    const float* Wq       = (const float*)d_in[5];
    const float* bq       = (const float*)d_in[6];
    const float* Wk       = (const float*)d_in[7];
    const float* bk       = (const float*)d_in[8];
    const float* Wv       = (const float*)d_in[9];
    const float* bv       = (const float*)d_in[10];
    const float* Wp       = (const float*)d_in[11];
    const float* bp       = (const float*)d_in[12];
    const float* Wo       = (const float*)d_in[13];
    const float* bo       = (const float*)d_in[14];
    const float* W_out    = (const float*)d_in[15];
    const float* b_out    = (const float*)d_in[16];

    // workspace carve (bf16 elements)
    __hip_bfloat16* featb = (__hip_bfloat16*)d_ws;       // 16384*64
    __hip_bfloat16* f     = featb + 1048576;             // 16384*256
    __hip_bfloat16* qkv   = f + 4194304;                 // 16384*768
    __hip_bfloat16* ob    = qkv + 12582912;              // 16384*256
    __hip_bfloat16* WtIn  = ob + 4194304;                // 256*64
    __hip_bfloat16* WtQKV = WtIn + 16384;                // 2*768*256
    __hip_bfloat16* WtO   = WtQKV + 393216;              // 2*256*256
    __hip_bfloat16* WtOut = WtO + 131072;                // 256*256

    prep_kernel<<<1616, 256, 0, stream>>>(W_in, Wq, Wk, Wv, Wo, W_out, features,
                                          WtIn, WtQKV, WtO, WtOut, featb);

    // f = features @ W_in + b_in
    gemm_mfma<64, false, false, false><<<dim3(2, 128), 256, 0, stream>>>(
        featb, WtIn, b_in, b_in, b_in, nullptr, f, BPTS, 256);

    for (int l = 0; l < 2; ++l) {
        gemm_mfma<256, false, false, false><<<dim3(6, 128), 256, 0, stream>>>(
            f, WtQKV + (size_t)l * 196608,
            bq + l * 256, bk + l * 256, bv + l * 256, nullptr, qkv, BPTS, 768);

        knn_attn_kernel<<<dim3(BPTS / 2), 256, 0, stream>>>(
            xyzs, k_graph, qkv, Wp + (size_t)l * 768, bp + l * 256, ob);

        // f = ob @ Wo + bo + f
        gemm_mfma<256, true, false, false><<<dim3(2, 128), 256, 0, stream>>>(
            ob, WtO + (size_t)l * 65536,
            bo + l * 256, bo + l * 256, bo + l * 256, f, f, BPTS, 256);
    }

    // out = leaky_relu(f @ W_out + b_out), fp32
    gemm_mfma<256, false, true, true><<<dim3(2, 128), 256, 0, stream>>>(
        f, WtOut, b_out, b_out, b_out, nullptr, (float*)d_out, BPTS, 256);
}

// Round 3
// 151.886 us; speedup vs baseline: 3.6147x; 1.2690x over previous
//
#include <hip/hip_runtime.h>
#include <hip/hip_bf16.h>

typedef __attribute__((ext_vector_type(8))) short bf16x8;
typedef __attribute__((ext_vector_type(4))) float f32x4;
typedef unsigned int uint;

constexpr int NPTS = 8192;
constexpr int BPTS = 16384;     // B*N
constexpr int KNN  = 16;

// async global->LDS, 16B per lane; LDS dest is wave-uniform base + lane*16.
__device__ __forceinline__ void gload16(const void* g, void* l) {
    __builtin_amdgcn_global_load_lds(
        (const __attribute__((address_space(1))) unsigned int*)g,
        (__attribute__((address_space(3))) unsigned int*)l, 16, 0, 0);
}

__device__ __forceinline__ float2 bf2f2(uint u) {
    float2 r;
    r.x = __uint_as_float(u << 16);
    r.y = __uint_as_float(u & 0xffff0000u);
    return r;
}

__device__ __forceinline__ uint packbf2(float a, float b) {
    union { __hip_bfloat16 h; unsigned short u; } ua, ub;
    ua.h = __float2bfloat16(a); ub.h = __float2bfloat16(b);
    return (uint)ua.u | ((uint)ub.u << 16);
}

// ---------------------------------------------------------------------------
// bf16 MFMA GEMM: C[M,N] = A[M,KD] @ Bt[N,KD]^T + bias (+res)(+lrelu)
// 128x128 tile, BK=64, 4 waves (2x2 of 64x64), 16x16x32 MFMA, fp32 acc.
// LDS rows are 64 bf16 = 8 x 16B slots; phys_slot = logical_slot ^ (row & 7)
// -> fragment b128 reads spread over all 32 banks. Staged via global_load_lds
// (linear LDS dest) with the inverse swizzle applied to the global address.
// ---------------------------------------------------------------------------
template<int KD, bool RES, bool OUTF32, bool LRELU>
__global__ __launch_bounds__(256) void gemm_mfma(
    const __hip_bfloat16* __restrict__ A,   // [M, KD]
    const __hip_bfloat16* __restrict__ Bt,  // [N, KD]  (W transposed)
    const float* __restrict__ b0, const float* __restrict__ b1,
    const float* __restrict__ b2,
    const __hip_bfloat16* __restrict__ res, // [M, N] or null
    void* __restrict__ Cout, int M, int N)
{
    __shared__ __align__(16) __hip_bfloat16 As[128 * 64];   // 16 KB
    __shared__ __align__(16) __hip_bfloat16 Bs[128 * 64];   // 16 KB

    const int tid  = threadIdx.x;
    const int lane = tid & 63;
    const int wid  = tid >> 6;
    const int wm   = (wid >> 1) * 64;
    const int wn   = (wid & 1) * 64;
    const int bm   = blockIdx.y * 128;
    const int bn   = blockIdx.x * 128;

    // staging: per pass, wave w covers 8 rows (1 KB). lane -> row 8w+(l>>3),
    // phys slot l&7 receives logical slot (l&7) ^ (row&7).
    const int srow8 = lane >> 3;                  // 0..7 (= row&7)
    const int sslot = (lane & 7) ^ srow8;

    // fragment read: row r = lane&15, k-group g = lane>>4 (0..3)
    const int r = lane & 15;
    const int g = lane >> 4;

    f32x4 acc[4][4] = {};

    for (int k0 = 0; k0 < KD; k0 += 64) {
        #pragma unroll
        for (int p = 0; p < 4; ++p) {
            const int rowA = p * 32 + wid * 8 + srow8;
            gload16(&A[(size_t)(bm + rowA) * KD + k0 + sslot * 8],
                    (char*)As + (p * 32 + wid * 8) * 128);
            gload16(&Bt[(size_t)(bn + rowA) * KD + k0 + sslot * 8],
                    (char*)Bs + (p * 32 + wid * 8) * 128);
        }
        __syncthreads();

        bf16x8 af[2][4], bfr[2][4];
        #pragma unroll
        for (int s = 0; s < 2; ++s) {
            const int physA = (s * 4 + g) ^ (r & 7);
            #pragma unroll
            for (int mi = 0; mi < 4; ++mi)
                af[s][mi] = *(const bf16x8*)((const char*)As + (wm + mi * 16 + r) * 128 + physA * 16);
            #pragma unroll
            for (int ni = 0; ni < 4; ++ni)
                bfr[s][ni] = *(const bf16x8*)((const char*)Bs + (wn + ni * 16 + r) * 128 + physA * 16);
        }
        #pragma unroll
        for (int s = 0; s < 2; ++s)
            #pragma unroll
            for (int mi = 0; mi < 4; ++mi)
                #pragma unroll
                for (int ni = 0; ni < 4; ++ni)
                    acc[mi][ni] = __builtin_amdgcn_mfma_f32_16x16x32_bf16(
                        af[s][mi], bfr[s][ni], acc[mi][ni], 0, 0, 0);
        __syncthreads();
    }

    // epilogue: C row = (lane>>4)*4 + reg, col = lane&15
    #pragma unroll
    for (int ni = 0; ni < 4; ++ni) {
        const int col = bn + wn + ni * 16 + r;
        const float* bsel = (col < 256) ? b0 : (col < 512 ? b1 : b2);
        const float bias = bsel[col & 255];
        #pragma unroll
        for (int mi = 0; mi < 4; ++mi) {
            #pragma unroll
            for (int q = 0; q < 4; ++q) {
                const int row = bm + wm + mi * 16 + g * 4 + q;
                float v = acc[mi][ni][q] + bias;
                if (RES)  v += __bfloat162float(res[(size_t)row * N + col]);
                if (LRELU) v = v > 0.f ? v : 0.01f * v;
                if (OUTF32) ((float*)Cout)[(size_t)row * N + col] = v;
                else ((__hip_bfloat16*)Cout)[(size_t)row * N + col] = __float2bfloat16(v);
            }
        }
    }
}

// ---------------------------------------------------------------------------
// prep: transpose-convert weights fp32[K][N] -> bf16[N][K]; features -> bf16.
// ---------------------------------------------------------------------------
__global__ __launch_bounds__(256) void prep_kernel(
    const float* __restrict__ W_in, const float* __restrict__ Wq,
    const float* __restrict__ Wk,  const float* __restrict__ Wv,
    const float* __restrict__ Wo,  const float* __restrict__ W_out,
    const float* __restrict__ features,
    __hip_bfloat16* __restrict__ WtIn,  __hip_bfloat16* __restrict__ WtQKV,
    __hip_bfloat16* __restrict__ WtO,   __hip_bfloat16* __restrict__ WtOut,
    __hip_bfloat16* __restrict__ featb)
{
    const int b = blockIdx.x;
    if (b < 592) {
        const float* srcs[10] = {W_in, Wq, Wk, Wv, Wq + 65536, Wk + 65536,
                                 Wv + 65536, Wo, Wo + 65536, W_out};
        __hip_bfloat16* dsts[10] = {
            WtIn, WtQKV, WtQKV + 65536, WtQKV + 131072,
            WtQKV + 196608, WtQKV + 262144, WtQKV + 327680,
            WtO, WtO + 65536, WtOut};
        const int Ks[10]    = {64,256,256,256,256,256,256,256,256,256};
        const int start[10] = {0,16,80,144,208,272,336,400,464,528};
        int j = 0;
        #pragma unroll
        for (int i = 1; i < 10; ++i) if (b >= start[i]) j = i;
        const int t  = b - start[j];
        const int Kd = Ks[j];
        const int ntk = Kd >> 5;
        const int tn = t / ntk;
        const int tk = t - tn * ntk;

        __shared__ float s[32][33];
        const int tx = threadIdx.x & 31, ty = threadIdx.x >> 5;
        const float* src = srcs[j];
        #pragma unroll
        for (int i = 0; i < 4; ++i)
            s[ty + i * 8][tx] = src[(size_t)(tk * 32 + ty + i * 8) * 256 + tn * 32 + tx];
        __syncthreads();
        __hip_bfloat16* dst = dsts[j];
        #pragma unroll
        for (int i = 0; i < 4; ++i)
            dst[(size_t)(tn * 32 + ty + i * 8) * Kd + tk * 32 + tx] =
                __float2bfloat16(s[tx][ty + i * 8]);
    } else {
        const int i = (b - 592) * 1024 + threadIdx.x * 4;
        const float4 v = *(const float4*)&features[i];
        __hip_bfloat16 tmp[4] = {__float2bfloat16(v.x), __float2bfloat16(v.y),
                                 __float2bfloat16(v.z), __float2bfloat16(v.w)};
        *(uint2*)&featb[i] = *(const uint2*)tmp;
    }
}

// ---------------------------------------------------------------------------
// KNN attention, algebraically folded positional encoding.
// 2 points / 256-thread block.  Phases:
//   setup: rel/rows (32 thr) + wq[h][4] = [Wp_j . q_head, bp . q_head] (64 thr)
//   stage: v rows -> LDS via global_load_lds (async, linear layout)
//   QK:    thread <-> (pt, head, k): logit = (q.k_nb + rel.wq + wq3)/sqrt(32)
//          softmax over the 16 lanes of the head; arel[h] = sum_k a_k rel_k
//   PV:    thread <-> (pt, ch pair): o = sum_k a_k v + arel.Wp + bp
// ---------------------------------------------------------------------------
__global__ __launch_bounds__(256) void knn_attn_kernel(
    const float* __restrict__ xyz,          // [BPTS,3]
    const int*   __restrict__ idx,          // [BPTS,KNN]
    const __hip_bfloat16* __restrict__ qkv, // [BPTS,768] = q|k|v
    const float* __restrict__ Wp,           // [3,256]
    const float* __restrict__ bp,           // [256]
    __hip_bfloat16* __restrict__ o)         // [BPTS,256]
{
    const int tid = threadIdx.x;
    const int pt  = tid >> 7;
    const int lt  = tid & 127;
    const int p0  = blockIdx.x * 2;
    const int p   = p0 + pt;

    __shared__ int   s_row[2][KNN];
    __shared__ float s_rel[2][KNN][3];
    __shared__ float s_wq[2][8][4];
    __shared__ float s_attn[2][8][KNN];
    __shared__ float s_arel[2][8][3];
    __shared__ __align__(16) __hip_bfloat16 v_lds[2][KNN][256];  // 16 KB

    // --- setup ---
    if (tid < 32) {
        const int pp = tid >> 4;
        const int kk = tid & 15;
        const int pg = p0 + pp;
        const int bidx = pg >> 13;
        const int j = idx[pg * KNN + kk];
        const int jrow = (bidx << 13) + j;
        s_row[pp][kk] = jrow;
        s_rel[pp][kk][0] = xyz[pg * 3 + 0] - xyz[jrow * 3 + 0];
        s_rel[pp][kk][1] = xyz[pg * 3 + 1] - xyz[jrow * 3 + 1];
        s_rel[pp][kk][2] = xyz[pg * 3 + 2] - xyz[jrow * 3 + 2];
    } else if (tid >= 64 && tid < 128) {
        const int t2 = tid - 64;
        const int pp = t2 >> 5;          // point
        const int hh = (t2 >> 2) & 7;    // head
        const int j  = t2 & 3;           // 0..2 = Wp row, 3 = bp
        const __hip_bfloat16* qrow = qkv + (size_t)(p0 + pp) * 768 + hh * 32;
        const float* w = (j < 3) ? (Wp + j * 256 + hh * 32) : (bp + hh * 32);
        float acc = 0.f;
        #pragma unroll
        for (int c = 0; c < 32; c += 2) {
            const float2 qf = bf2f2(*(const uint*)&qrow[c]);
            acc += qf.x * w[c] + qf.y * w[c + 1];
        }
        s_wq[pp][hh][j] = acc;
    }
    __syncthreads();

    // --- stage V rows into LDS (async; drained by the next barrier) ---
    {
        const int wv  = tid >> 6, ln = tid & 63;
        const int ptw = wv >> 1;
        const int rb  = (wv & 1) * 8;
        #pragma unroll
        for (int c = 0; c < 4; ++c) {
            const int kk = rb + c * 2 + (ln >> 5);
            const int jr = s_row[ptw][kk];
            gload16(qkv + (size_t)jr * 768 + 512 + (ln & 31) * 8,
                    (char*)&v_lds[ptw][rb + c * 2][0]);
        }
    }

    // --- QK phase: thread = (pt, h, k) ---
    const int h = lt >> 4;
    const int k = lt & 15;
    {
        const int jrow = s_row[pt][k];
        const uint4* qp = (const uint4*)(qkv + (size_t)p * 768 + h * 32);
        const uint4* kp = (const uint4*)(qkv + (size_t)jrow * 768 + 256 + h * 32);
        float dot = 0.f;
        #pragma unroll
        for (int i = 0; i < 4; ++i) {
            const uint4 qu = qp[i], ku = kp[i];
            float2 qf, kf;
            qf = bf2f2(qu.x); kf = bf2f2(ku.x); dot += qf.x * kf.x + qf.y * kf.y;
            qf = bf2f2(qu.y); kf = bf2f2(ku.y); dot += qf.x * kf.x + qf.y * kf.y;
            qf = bf2f2(qu.z); kf = bf2f2(ku.z); dot += qf.x * kf.x + qf.y * kf.y;
            qf = bf2f2(qu.w); kf = bf2f2(ku.w); dot += qf.x * kf.x + qf.y * kf.y;
        }
        const float r0 = s_rel[pt][k][0], r1 = s_rel[pt][k][1], r2 = s_rel[pt][k][2];
        const float logit = (dot + r0 * s_wq[pt][h][0] + r1 * s_wq[pt][h][1]
                                 + r2 * s_wq[pt][h][2] + s_wq[pt][h][3])
                            * 0.1767766952966369f;
        float mx = logit;
        #pragma unroll
        for (int off = 8; off >= 1; off >>= 1)
            mx = fmaxf(mx, __shfl_xor(mx, off, 16));
        const float e = __expf(logit - mx);
        float den = e;
        #pragma unroll
        for (int off = 8; off >= 1; off >>= 1)
            den += __shfl_xor(den, off, 16);
        const float attn = e / den;
        s_attn[pt][h][k] = attn;

        float a0 = attn * r0, a1 = attn * r1, a2 = attn * r2;
        #pragma unroll
        for (int off = 8; off >= 1; off >>= 1) {
            a0 += __shfl_xor(a0, off, 16);
            a1 += __shfl_xor(a1, off, 16);
            a2 += __shfl_xor(a2, off, 16);
        }
        if (k == 0) {
            s_arel[pt][h][0] = a0;
            s_arel[pt][h][1] = a1;
            s_arel[pt][h][2] = a2;
        }
    }
    __syncthreads();   // also drains the async v-stage (vmcnt 0 before barrier)

    // --- PV phase: thread = (pt, channel pair) ---
    {
        const int ch = lt * 2;
        float ax = 0.f, ay = 0.f;
        #pragma unroll
        for (int kk = 0; kk < KNN; ++kk) {
            const float a = s_attn[pt][h][kk];
            const float2 vf = bf2f2(*(const uint*)&v_lds[pt][kk][ch]);
            ax += a * vf.x;
            ay += a * vf.y;
        }
        const float2 wp0 = *(const float2*)&Wp[ch];
        const float2 wp1 = *(const float2*)&Wp[256 + ch];
        const float2 wp2 = *(const float2*)&Wp[512 + ch];
        const float2 bpv = *(const float2*)&bp[ch];
        const float r0 = s_arel[pt][h][0], r1 = s_arel[pt][h][1], r2 = s_arel[pt][h][2];
        ax += r0 * wp0.x + r1 * wp1.x + r2 * wp2.x + bpv.x;
        ay += r0 * wp0.y + r1 * wp1.y + r2 * wp2.y + bpv.y;
        *(uint*)&o[(size_t)p * 256 + ch] = packbf2(ax, ay);
    }
}

// ---------------------------------------------------------------------------
extern "C" void kernel_launch(void* const* d_in, const int* in_sizes, int n_in,
                              void* d_out, int out_size, void* d_ws, size_t ws_size,
                              hipStream_t stream)
{
    const float* xyzs     = (const float*)d_in[0];
    const float* features = (const float*)d_in[1];
    const int*   k_graph  = (const int*)  d_in[2];
    const float* W_in     = (const float*)d_in[3];
    const float* b_in     = (const float*)d_in[4];
    const float* Wq       = (const float*)d_in[5];
    const float* bq       = (const float*)d_in[6];
    const float* Wk       = (const float*)d_in[7];
    const float* bk       = (const float*)d_in[8];
    const float* Wv       = (const float*)d_in[9];
    const float* bv       = (const float*)d_in[10];
    const float* Wp       = (const float*)d_in[11];
    const float* bp       = (const float*)d_in[12];
    const float* Wo       = (const float*)d_in[13];
    const float* bo       = (const float*)d_in[14];
    const float* W_out    = (const float*)d_in[15];
    const float* b_out    = (const float*)d_in[16];

    __hip_bfloat16* featb = (__hip_bfloat16*)d_ws;       // 16384*64
    __hip_bfloat16* f     = featb + 1048576;             // 16384*256
    __hip_bfloat16* qkv   = f + 4194304;                 // 16384*768
    __hip_bfloat16* ob    = qkv + 12582912;              // 16384*256
    __hip_bfloat16* WtIn  = ob + 4194304;                // 256*64
    __hip_bfloat16* WtQKV = WtIn + 16384;                // 2*768*256
    __hip_bfloat16* WtO   = WtQKV + 393216;              // 2*256*256
    __hip_bfloat16* WtOut = WtO + 131072;                // 256*256

    prep_kernel<<<1616, 256, 0, stream>>>(W_in, Wq, Wk, Wv, Wo, W_out, features,
                                          WtIn, WtQKV, WtO, WtOut, featb);

    // f = features @ W_in + b_in
    gemm_mfma<64, false, false, false><<<dim3(2, 128), 256, 0, stream>>>(
        featb, WtIn, b_in, b_in, b_in, nullptr, f, BPTS, 256);

    for (int l = 0; l < 2; ++l) {
        gemm_mfma<256, false, false, false><<<dim3(6, 128), 256, 0, stream>>>(
            f, WtQKV + (size_t)l * 196608,
            bq + l * 256, bk + l * 256, bv + l * 256, nullptr, qkv, BPTS, 768);

        knn_attn_kernel<<<dim3(BPTS / 2), 256, 0, stream>>>(
            xyzs, k_graph, qkv, Wp + (size_t)l * 768, bp + l * 256, ob);

        // f = ob @ Wo + bo + f
        gemm_mfma<256, true, false, false><<<dim3(2, 128), 256, 0, stream>>>(
            ob, WtO + (size_t)l * 65536,
            bo + l * 256, bo + l * 256, bo + l * 256, f, f, BPTS, 256);
    }

    // out = leaky_relu(f @ W_out + b_out), fp32
    gemm_mfma<256, false, true, true><<<dim3(2, 128), 256, 0, stream>>>(
        f, WtOut, b_out, b_out, b_out, nullptr, (float*)d_out, BPTS, 256);
}

// Round 4
// 131.554 us; speedup vs baseline: 4.1734x; 1.1546x over previous
//
#include <hip/hip_runtime.h>
#include <hip/hip_bf16.h>

typedef __attribute__((ext_vector_type(8))) short bf16x8;
typedef __attribute__((ext_vector_type(4))) float f32x4;
typedef __attribute__((ext_vector_type(2))) _Float16 h2;
typedef __attribute__((ext_vector_type(8))) _Float16 h8;
typedef unsigned int uint;

constexpr int NPTS = 8192;
constexpr int BPTS = 16384;     // B*N
constexpr int KNN  = 16;

// async global->LDS, 16B per lane; LDS dest is wave-uniform base + lane*16.
__device__ __forceinline__ void gload16(const void* g, void* l) {
    __builtin_amdgcn_global_load_lds(
        (const __attribute__((address_space(1))) unsigned int*)g,
        (__attribute__((address_space(3))) unsigned int*)l, 16, 0, 0);
}

__device__ __forceinline__ uint packbf2(float a, float b) {
    union { __hip_bfloat16 h; unsigned short u; } ua, ub;
    ua.h = __float2bfloat16(a); ub.h = __float2bfloat16(b);
    return (uint)ua.u | ((uint)ub.u << 16);
}

// ---------------------------------------------------------------------------
// bf16 MFMA GEMM: C[M,N] = A[M,KD] @ Bt[N,KD]^T + bias (+res)
// 128x128 tile, BK=64, 4 waves, 16x16x32 MFMA, fp32 acc, XOR-swizzled LDS.
// OUTT: 0 = f32, 1 = bf16, 2 = f16
// ---------------------------------------------------------------------------
template<int KD, bool RES, int OUTT, bool LRELU>
__global__ __launch_bounds__(256) void gemm_mfma(
    const __hip_bfloat16* __restrict__ A,   // [M, KD]
    const __hip_bfloat16* __restrict__ Bt,  // [N, KD]
    const float* __restrict__ b0, const float* __restrict__ b1,
    const float* __restrict__ b2,
    const __hip_bfloat16* __restrict__ res, // [M, N] or null
    void* __restrict__ Cout, int M, int N)
{
    __shared__ __align__(16) __hip_bfloat16 As[128 * 64];
    __shared__ __align__(16) __hip_bfloat16 Bs[128 * 64];

    const int tid  = threadIdx.x;
    const int lane = tid & 63;
    const int wid  = tid >> 6;
    const int wm   = (wid >> 1) * 64;
    const int wn   = (wid & 1) * 64;
    const int bm   = blockIdx.y * 128;
    const int bn   = blockIdx.x * 128;

    const int srow8 = lane >> 3;
    const int sslot = (lane & 7) ^ srow8;
    const int r = lane & 15;
    const int g = lane >> 4;

    f32x4 acc[4][4] = {};

    for (int k0 = 0; k0 < KD; k0 += 64) {
        #pragma unroll
        for (int p = 0; p < 4; ++p) {
            const int rowA = p * 32 + wid * 8 + srow8;
            gload16(&A[(size_t)(bm + rowA) * KD + k0 + sslot * 8],
                    (char*)As + (p * 32 + wid * 8) * 128);
            gload16(&Bt[(size_t)(bn + rowA) * KD + k0 + sslot * 8],
                    (char*)Bs + (p * 32 + wid * 8) * 128);
        }
        __syncthreads();

        bf16x8 af[2][4], bfr[2][4];
        #pragma unroll
        for (int s = 0; s < 2; ++s) {
            const int physA = (s * 4 + g) ^ (r & 7);
            #pragma unroll
            for (int mi = 0; mi < 4; ++mi)
                af[s][mi] = *(const bf16x8*)((const char*)As + (wm + mi * 16 + r) * 128 + physA * 16);
            #pragma unroll
            for (int ni = 0; ni < 4; ++ni)
                bfr[s][ni] = *(const bf16x8*)((const char*)Bs + (wn + ni * 16 + r) * 128 + physA * 16);
        }
        #pragma unroll
        for (int s = 0; s < 2; ++s)
            #pragma unroll
            for (int mi = 0; mi < 4; ++mi)
                #pragma unroll
                for (int ni = 0; ni < 4; ++ni)
                    acc[mi][ni] = __builtin_amdgcn_mfma_f32_16x16x32_bf16(
                        af[s][mi], bfr[s][ni], acc[mi][ni], 0, 0, 0);
        __syncthreads();
    }

    #pragma unroll
    for (int ni = 0; ni < 4; ++ni) {
        const int col = bn + wn + ni * 16 + r;
        const float* bsel = (col < 256) ? b0 : (col < 512 ? b1 : b2);
        const float bias = bsel[col & 255];
        #pragma unroll
        for (int mi = 0; mi < 4; ++mi) {
            #pragma unroll
            for (int q = 0; q < 4; ++q) {
                const int row = bm + wm + mi * 16 + g * 4 + q;
                float v = acc[mi][ni][q] + bias;
                if (RES)  v += __bfloat162float(res[(size_t)row * N + col]);
                if (LRELU) v = v > 0.f ? v : 0.01f * v;
                if (OUTT == 0)      ((float*)Cout)[(size_t)row * N + col] = v;
                else if (OUTT == 1) ((__hip_bfloat16*)Cout)[(size_t)row * N + col] = __float2bfloat16(v);
                else                ((_Float16*)Cout)[(size_t)row * N + col] = (_Float16)v;
            }
        }
    }
}

// ---------------------------------------------------------------------------
// prep: weights fp32[K][N] -> bf16[N][K]; features -> bf16; Wp/bp -> f16 rows.
// ---------------------------------------------------------------------------
__global__ __launch_bounds__(256) void prep_kernel(
    const float* __restrict__ W_in, const float* __restrict__ Wq,
    const float* __restrict__ Wk,  const float* __restrict__ Wv,
    const float* __restrict__ Wo,  const float* __restrict__ W_out,
    const float* __restrict__ features,
    const float* __restrict__ Wp,  const float* __restrict__ bp,
    __hip_bfloat16* __restrict__ WtIn,  __hip_bfloat16* __restrict__ WtQKV,
    __hip_bfloat16* __restrict__ WtO,   __hip_bfloat16* __restrict__ WtOut,
    __hip_bfloat16* __restrict__ featb, _Float16* __restrict__ Wpb)
{
    const int b = blockIdx.x;
    if (b < 592) {
        const float* srcs[10] = {W_in, Wq, Wk, Wv, Wq + 65536, Wk + 65536,
                                 Wv + 65536, Wo, Wo + 65536, W_out};
        __hip_bfloat16* dsts[10] = {
            WtIn, WtQKV, WtQKV + 65536, WtQKV + 131072,
            WtQKV + 196608, WtQKV + 262144, WtQKV + 327680,
            WtO, WtO + 65536, WtOut};
        const int Ks[10]    = {64,256,256,256,256,256,256,256,256,256};
        const int start[10] = {0,16,80,144,208,272,336,400,464,528};
        int j = 0;
        #pragma unroll
        for (int i = 1; i < 10; ++i) if (b >= start[i]) j = i;
        const int t  = b - start[j];
        const int Kd = Ks[j];
        const int ntk = Kd >> 5;
        const int tn = t / ntk;
        const int tk = t - tn * ntk;

        __shared__ float s[32][33];
        const int tx = threadIdx.x & 31, ty = threadIdx.x >> 5;
        const float* src = srcs[j];
        #pragma unroll
        for (int i = 0; i < 4; ++i)
            s[ty + i * 8][tx] = src[(size_t)(tk * 32 + ty + i * 8) * 256 + tn * 32 + tx];
        __syncthreads();
        __hip_bfloat16* dst = dsts[j];
        #pragma unroll
        for (int i = 0; i < 4; ++i)
            dst[(size_t)(tn * 32 + ty + i * 8) * Kd + tk * 32 + tx] =
                __float2bfloat16(s[tx][ty + i * 8]);
    } else if (b < 1616) {
        const int i = (b - 592) * 1024 + threadIdx.x * 4;
        const float4 v = *(const float4*)&features[i];
        __hip_bfloat16 tmp[4] = {__float2bfloat16(v.x), __float2bfloat16(v.y),
                                 __float2bfloat16(v.z), __float2bfloat16(v.w)};
        *(uint2*)&featb[i] = *(const uint2*)tmp;
    } else {
        // Wp (L,3,256) + bp (L,256) -> Wpb[l][4][256] f16 (row 3 = bp)
        const int e8 = threadIdx.x * 8;          // 2048 elems
        const int l  = e8 >> 10;
        const int rr = (e8 >> 8) & 3;
        const int c  = e8 & 255;
        const float* src = (rr < 3) ? (Wp + (size_t)l * 768 + rr * 256 + c)
                                    : (bp + (size_t)l * 256 + c);
        const float4 f0 = ((const float4*)src)[0];
        const float4 f1 = ((const float4*)src)[1];
        _Float16 t[8] = {(_Float16)f0.x, (_Float16)f0.y, (_Float16)f0.z, (_Float16)f0.w,
                         (_Float16)f1.x, (_Float16)f1.y, (_Float16)f1.z, (_Float16)f1.w};
        *(uint4*)&Wpb[(size_t)l * 1024 + rr * 256 + c] = *(const uint4*)t;
    }
}

// ---------------------------------------------------------------------------
// KNN attention, f16 qkv, folded positional encoding, 2 barriers.
//   all threads: jrow from idx, issue q/k loads, issue async V->LDS stage;
//   threads 0-31: rel; threads 32-95: wq[pt][h][4] via fdot2;
//   all: QK dot via fdot2. barrier. softmax + arel. barrier. PV from LDS.
// ---------------------------------------------------------------------------
__global__ __launch_bounds__(256) void knn_attn_kernel(
    const float* __restrict__ xyz,        // [BPTS,3]
    const int*   __restrict__ idx,        // [BPTS,KNN]
    const _Float16* __restrict__ qkv,     // [BPTS,768] = q|k|v
    const _Float16* __restrict__ Wpb,     // [4][256]  (Wp rows + bp)
    __hip_bfloat16* __restrict__ o)       // [BPTS,256]
{
    const int tid = threadIdx.x;
    const int pt  = tid >> 7;
    const int lt  = tid & 127;
    const int p0  = blockIdx.x * 2;
    const int p   = p0 + pt;
    const int h   = lt >> 4;
    const int k   = lt & 15;

    __shared__ float s_rel[2][KNN][3];
    __shared__ float s_wq[2][8][4];
    __shared__ float s_attn[2][8][KNN];
    __shared__ float s_arel[2][8][3];
    __shared__ __align__(16) _Float16 v_lds[2][KNN][256];  // 16 KB

    // --- QK loads (oldest in flight) ---
    const int jrow = ((p >> 13) << 13) + idx[p * KNN + k];
    const h8* qp = (const h8*)(qkv + (size_t)p * 768 + h * 32);
    const h8* kp = (const h8*)(qkv + (size_t)jrow * 768 + 256 + h * 32);
    const h8 q0 = qp[0], q1 = qp[1];
    const h8 k0 = kp[0], k1 = kp[1];

    // --- async V staging: 32 rows x 512B; wave covers 8 rows ---
    {
        const int w = tid >> 6, ln = tid & 63;
        #pragma unroll
        for (int c = 0; c < 4; ++c) {
            const int grE = w * 8 + c * 2;              // even row id 0..30
            const int gr  = grE + (ln >> 5);
            const int ptw = grE >> 4, kkE = grE & 15;
            const int pg  = p0 + (gr >> 4);
            const int jr  = ((pg >> 13) << 13) + idx[pg * KNN + (gr & 15)];
            gload16(qkv + (size_t)jr * 768 + 512 + (ln & 31) * 8,
                    (char*)&v_lds[ptw][kkE][0]);
        }
    }

    // --- side computations while loads fly ---
    if (tid < 32) {
        const int pp = tid >> 4, kk = tid & 15;
        const int pg = p0 + pp;
        const int jr = ((pg >> 13) << 13) + idx[pg * KNN + kk];
        s_rel[pp][kk][0] = xyz[pg * 3 + 0] - xyz[jr * 3 + 0];
        s_rel[pp][kk][1] = xyz[pg * 3 + 1] - xyz[jr * 3 + 1];
        s_rel[pp][kk][2] = xyz[pg * 3 + 2] - xyz[jr * 3 + 2];
    } else if (tid < 96) {
        const int t2 = tid - 32;
        const int pp = t2 >> 5, hh = (t2 >> 2) & 7, j = t2 & 3;
        const h8* qr = (const h8*)(qkv + (size_t)(p0 + pp) * 768 + hh * 32);
        const h8* wr = (const h8*)(Wpb + j * 256 + hh * 32);
        const h8 a0 = qr[0], a1 = qr[1], b0 = wr[0], b1 = wr[1];
        float acc = 0.f;
        #pragma unroll
        for (int i = 0; i < 4; ++i)
            acc = __builtin_amdgcn_fdot2(((const h2*)&a0)[i], ((const h2*)&b0)[i], acc, false);
        #pragma unroll
        for (int i = 0; i < 4; ++i)
            acc = __builtin_amdgcn_fdot2(((const h2*)&a1)[i], ((const h2*)&b1)[i], acc, false);
        s_wq[pp][hh][j] = acc;
    }

    // --- QK dot (fdot2) ---
    float dot = 0.f;
    #pragma unroll
    for (int i = 0; i < 4; ++i)
        dot = __builtin_amdgcn_fdot2(((const h2*)&q0)[i], ((const h2*)&k0)[i], dot, false);
    #pragma unroll
    for (int i = 0; i < 4; ++i)
        dot = __builtin_amdgcn_fdot2(((const h2*)&q1)[i], ((const h2*)&k1)[i], dot, false);
    __syncthreads();

    // --- logit + softmax + arel ---
    const float r0 = s_rel[pt][k][0], r1 = s_rel[pt][k][1], r2 = s_rel[pt][k][2];
    const float logit = (dot + r0 * s_wq[pt][h][0] + r1 * s_wq[pt][h][1]
                             + r2 * s_wq[pt][h][2] + s_wq[pt][h][3])
                        * 0.1767766952966369f;
    float mx = logit;
    #pragma unroll
    for (int off = 8; off >= 1; off >>= 1)
        mx = fmaxf(mx, __shfl_xor(mx, off, 16));
    const float e = __expf(logit - mx);
    float den = e;
    #pragma unroll
    for (int off = 8; off >= 1; off >>= 1)
        den += __shfl_xor(den, off, 16);
    const float attn = e / den;
    s_attn[pt][h][k] = attn;

    float a0 = attn * r0, a1 = attn * r1, a2 = attn * r2;
    #pragma unroll
    for (int off = 8; off >= 1; off >>= 1) {
        a0 += __shfl_xor(a0, off, 16);
        a1 += __shfl_xor(a1, off, 16);
        a2 += __shfl_xor(a2, off, 16);
    }
    if (k == 0) {
        s_arel[pt][h][0] = a0;
        s_arel[pt][h][1] = a1;
        s_arel[pt][h][2] = a2;
    }
    __syncthreads();   // drains async V stage too

    // --- PV: thread = (pt, channel pair); head of ch == h ---
    {
        const int ch = lt * 2;
        float ax = 0.f, ay = 0.f;
        #pragma unroll
        for (int kk = 0; kk < KNN; ++kk) {
            const float a = s_attn[pt][h][kk];
            const h2 vf = *(const h2*)&v_lds[pt][kk][ch];
            ax += a * (float)vf.x;
            ay += a * (float)vf.y;
        }
        const h2 w0 = *(const h2*)&Wpb[ch];
        const h2 w1 = *(const h2*)&Wpb[256 + ch];
        const h2 w2 = *(const h2*)&Wpb[512 + ch];
        const h2 w3 = *(const h2*)&Wpb[768 + ch];
        const float g0 = s_arel[pt][h][0], g1 = s_arel[pt][h][1], g2 = s_arel[pt][h][2];
        ax += g0 * (float)w0.x + g1 * (float)w1.x + g2 * (float)w2.x + (float)w3.x;
        ay += g0 * (float)w0.y + g1 * (float)w1.y + g2 * (float)w2.y + (float)w3.y;
        *(uint*)&o[(size_t)p * 256 + ch] = packbf2(ax, ay);
    }
}

// ---------------------------------------------------------------------------
extern "C" void kernel_launch(void* const* d_in, const int* in_sizes, int n_in,
                              void* d_out, int out_size, void* d_ws, size_t ws_size,
                              hipStream_t stream)
{
    const float* xyzs     = (const float*)d_in[0];
    const float* features = (const float*)d_in[1];
    const int*   k_graph  = (const int*)  d_in[2];
    const float* W_in     = (const float*)d_in[3];
    const float* b_in     = (const float*)d_in[4];
    const float* Wq       = (const float*)d_in[5];
    const float* bq       = (const float*)d_in[6];
    const float* Wk       = (const float*)d_in[7];
    const float* bk       = (const float*)d_in[8];
    const float* Wv       = (const float*)d_in[9];
    const float* bv       = (const float*)d_in[10];
    const float* Wp       = (const float*)d_in[11];
    const float* bp       = (const float*)d_in[12];
    const float* Wo       = (const float*)d_in[13];
    const float* bo       = (const float*)d_in[14];
    const float* W_out    = (const float*)d_in[15];
    const float* b_out    = (const float*)d_in[16];

    __hip_bfloat16* featb = (__hip_bfloat16*)d_ws;       // 16384*64
    __hip_bfloat16* f     = featb + 1048576;             // 16384*256
    _Float16*       qkv   = (_Float16*)(f + 4194304);    // 16384*768 (f16)
    __hip_bfloat16* ob    = (__hip_bfloat16*)(qkv + 12582912);  // 16384*256
    __hip_bfloat16* WtIn  = ob + 4194304;                // 256*64
    __hip_bfloat16* WtQKV = WtIn + 16384;                // 2*768*256
    __hip_bfloat16* WtO   = WtQKV + 393216;              // 2*256*256
    __hip_bfloat16* WtOut = WtO + 131072;                // 256*256
    _Float16*       Wpb   = (_Float16*)(WtOut + 65536);  // 2*1024

    prep_kernel<<<1617, 256, 0, stream>>>(W_in, Wq, Wk, Wv, Wo, W_out, features,
                                          Wp, bp, WtIn, WtQKV, WtO, WtOut,
                                          featb, Wpb);

    // f = features @ W_in + b_in
    gemm_mfma<64, false, 1, false><<<dim3(2, 128), 256, 0, stream>>>(
        featb, WtIn, b_in, b_in, b_in, nullptr, f, BPTS, 256);

    for (int l = 0; l < 2; ++l) {
        gemm_mfma<256, false, 2, false><<<dim3(6, 128), 256, 0, stream>>>(
            f, WtQKV + (size_t)l * 196608,
            bq + l * 256, bk + l * 256, bv + l * 256, nullptr, qkv, BPTS, 768);

        knn_attn_kernel<<<dim3(BPTS / 2), 256, 0, stream>>>(
            xyzs, k_graph, qkv, Wpb + (size_t)l * 1024, ob);

        // f = ob @ Wo + bo + f
        gemm_mfma<256, true, 1, false><<<dim3(2, 128), 256, 0, stream>>>(
            ob, WtO + (size_t)l * 65536,
            bo + l * 256, bo + l * 256, bo + l * 256, f, f, BPTS, 256);
    }

    // out = leaky_relu(f @ W_out + b_out), fp32
    gemm_mfma<256, false, 0, true><<<dim3(2, 128), 256, 0, stream>>>(
        f, WtOut, b_out, b_out, b_out, nullptr, (float*)d_out, BPTS, 256);
}